// Round 11
// baseline (258.095 us; speedup 1.0000x reference)
//
#include <hip/hip_runtime.h>
#include <math.h>

#define HW    409600      // 640*640
#define HW4   102400      // float4-quads per (batch,dim)
#define BATCH 8
#define NLAB  33
#define GXB   100         // blocks per batch; 4 quads (16 px) per thread
#define NBLK  (GXB * BATCH)   // 800 blocks <= 1024 co-resident (4/CU via launch_bounds)
#define NREP  16          // LDS bin replicas (per 4-lane cluster)
#define RS    201         // replica stride (9r mod 32 bank offset between replicas)
// ws float-offset layout:
#define CTR_OFF   0       // u32 grid-barrier counter (zeroed per launch)
#define AWS_OFF   1344    // [8][208] global atomic bins

#if defined(__has_builtin) && __has_builtin(__builtin_amdgcn_sched_barrier)
#define SCHED_PIN() __builtin_amdgcn_sched_barrier(0)
#else
#define SCHED_PIN()
#endif

// Native fp32 atomic add (ds_add_f32 / global_atomic_add_f32) — avoids the
// CAS-loop expansion hipcc emits for atomicAdd(float*) without
// -munsafe-fp-atomics.
__device__ __forceinline__ void atomAddF(float* p, float v) {
    unsafeAtomicAdd(p, v);
}

__device__ __forceinline__ float getc(const float4& v, int e) {
    return (e == 0) ? v.x : (e == 1) ? v.y : (e == 2) ? v.z : v.w;
}
__device__ __forceinline__ float wave_sum(float v) {
    #pragma unroll
    for (int o = 32; o > 0; o >>= 1) v += __shfl_xor(v, o);
    return v;
}

__device__ __forceinline__ void acc1(int l, bool k,
                                     float x0, float x1, float x2, float x3,
                                     float* mb) {
    if (l) {
        float* bb = mb + l * 6;
        // packed counts: cnt_k in high 16, cnt_i in low 16 (per-block <= 4096,
        // so replica sums cannot carry into bit 16)
        atomicAdd((unsigned*)(bb + 4), k ? 0x10001u : 1u);   // ds_add_u32, native
        if (k) {
            atomAddF(bb + 0, x0);
            atomAddF(bb + 1, x1);
            atomAddF(bb + 2, x2);
            atomAddF(bb + 3, x3);
        }
    }
}

// phase-1 per-quad: label from iv/tv, bin into LDS replicas, return packed label
__device__ __forceinline__ unsigned procQ1(const int4& iv, const float4& tv,
                                           const float4& kv, const float4 x[4],
                                           float* mb) {
    int l0 = (tv.x > 0.5f) ? iv.x : 0;
    int l1 = (tv.y > 0.5f) ? iv.y : 0;
    int l2 = (tv.z > 0.5f) ? iv.z : 0;
    int l3 = (tv.w > 0.5f) ? iv.w : 0;
    acc1(l0, kv.x > 0.5f, x[0].x, x[1].x, x[2].x, x[3].x, mb);
    acc1(l1, kv.y > 0.5f, x[0].y, x[1].y, x[2].y, x[3].y, mb);
    acc1(l2, kv.z > 0.5f, x[0].z, x[1].z, x[2].z, x[3].z, mb);
    acc1(l3, kv.w > 0.5f, x[0].w, x[1].w, x[2].w, x[3].w, mb);
    return (unsigned)l0 | ((unsigned)l1 << 8) |
           ((unsigned)l2 << 16) | ((unsigned)l3 << 24);
}

// phase-2 per-quad: val from register-held emb + packed label
__device__ __forceinline__ float procQ2(unsigned pk, const float4 x[4],
                                        const float4* means4, const float* invci) {
    float acc = 0.f;
    #pragma unroll
    for (int e = 0; e < 4; ++e) {
        int l = (pk >> (8 * e)) & 255;
        if (l) {
            float4 m = means4[l];
            float d0 = getc(x[0], e) - m.x, d1 = getc(x[1], e) - m.y;
            float d2 = getc(x[2], e) - m.z, d3 = getc(x[3], e) - m.w;
            float dist = sqrtf(d0 * d0 + d1 * d1 + d2 * d2 + d3 * d3);
            float u = fmaxf(dist - 0.5f, 0.f);
            acc += __logf(u * u + 1.f) * invci[l];
        }
    }
    return acc;
}

__global__ __launch_bounds__(256, 4) void fused(const float* __restrict__ emb,
                                                const int*   __restrict__ inst,
                                                const float* __restrict__ kern,
                                                const float* __restrict__ tmask,
                                                float*       __restrict__ ws,
                                                float*       __restrict__ out) {
    __shared__ float  bins[NREP][RS];     // phase1 bins; raw[] reused in phase2
    __shared__ float4 means4[NLAB];
    __shared__ float  invci[NLAB];
    __shared__ float  red[4];
    const int t = threadIdx.x, bx = blockIdx.x, b = blockIdx.y;
    float* mb = bins[(t >> 2) & (NREP - 1)];   // 4 lanes per replica

    const size_t  base  = (size_t)b * HW;
    const float4* emb4  = (const float4*)(emb + base * 4);
    const int4*   inst4 = (const int4*)(inst + base);
    const float4* kern4 = (const float4*)(kern + base);
    const float4* tm4   = (const float4*)(tmask + base);
    const int g0 = bx * 1024 + t;              // quads: g0 + c*256, c=0..3

    // ---- persist all 16 emb float4s in registers (fully unrolled => VGPRs) ----
    float4 xq[4][4];
    #pragma unroll
    for (int c = 0; c < 4; ++c) {
        const int g = g0 + c * 256;
        #pragma unroll
        for (int d = 0; d < 4; ++d) xq[c][d] = emb4[g + d * HW4];
    }
    // masks for quads 0,1 prefetched; 2,3 loaded during processing
    int4   iv0 = inst4[g0],        iv1 = inst4[g0 + 256];
    float4 tv0 = tm4[g0],          tv1 = tm4[g0 + 256];
    float4 kv0 = kern4[g0],        kv1 = kern4[g0 + 256];
    SCHED_PIN();

    for (int i = t; i < NREP * RS; i += 256) (&bins[0][0])[i] = 0.f;
    __syncthreads();

    unsigned pk0 = procQ1(iv0, tv0, kv0, xq[0], mb);
    int4   iv2 = inst4[g0 + 512];
    float4 tv2 = tm4[g0 + 512];
    float4 kv2 = kern4[g0 + 512];
    SCHED_PIN();
    unsigned pk1 = procQ1(iv1, tv1, kv1, xq[1], mb);
    int4   iv3 = inst4[g0 + 768];
    float4 tv3 = tm4[g0 + 768];
    float4 kv3 = kern4[g0 + 768];
    SCHED_PIN();
    unsigned pk2 = procQ1(iv2, tv2, kv2, xq[2], mb);
    unsigned pk3 = procQ1(iv3, tv3, kv3, xq[3], mb);
    __syncthreads();

    // ---- phase-1 epilogue: replica-reduce -> global atomic bins ----
    if (t < NLAB * 6) {
        const int l = t / 6, k = t - l * 6;
        float v;
        if (k >= 4) {
            unsigned s = 0;
            #pragma unroll
            for (int r = 0; r < NREP; ++r)
                s += ((const unsigned*)bins[r])[l * 6 + 4];
            v = (k == 4) ? (float)(s >> 16) : (float)(s & 0xffffu);
        } else {
            float fs = 0.f;
            #pragma unroll
            for (int r = 0; r < NREP; ++r) fs += bins[r][l * 6 + k];
            v = fs;
        }
        if (v != 0.f) atomAddF(ws + AWS_OFF + b * 208 + t, v);
    }
    __syncthreads();   // drains each wave's outstanding global atomics (vmcnt)

    // ---- software grid barrier (device-scope; coop launch is rejected under
    //      graph capture). 800 blocks are all co-resident: launch_bounds(256,4)
    //      guarantees 4 blocks/CU x 256 CU = 1024 slots. ----
    unsigned* ctr = (unsigned*)(ws + CTR_OFF);
    if (t == 0) {
        __threadfence();                                   // release block's writes
        __hip_atomic_fetch_add(ctr, 1u, __ATOMIC_ACQ_REL,
                               __HIP_MEMORY_SCOPE_AGENT);
        while (__hip_atomic_load(ctr, __ATOMIC_ACQUIRE,
                                 __HIP_MEMORY_SCOPE_AGENT) < NBLK)
            __builtin_amdgcn_s_sleep(8);
        __threadfence();
    }
    __syncthreads();

    // ---- means/invci from AWS bins (acquire loads; reuse bins LDS as raw[]) ----
    float* raw = &bins[0][0];
    if (t < NLAB * 6)
        raw[t] = __hip_atomic_load(ws + AWS_OFF + b * 208 + t,
                                   __ATOMIC_ACQUIRE, __HIP_MEMORY_SCOPE_AGENT);
    __syncthreads();
    if (t < NLAB) {
        float cntk = raw[t * 6 + 4], cnti = raw[t * 6 + 5];
        float inv = 1.f / fmaxf(cntk, 1.f);
        float z = (t == 0) ? 0.f : 1.f;
        float4 m;
        m.x = z * raw[t * 6 + 0] * inv;
        m.y = z * raw[t * 6 + 1] * inv;
        m.z = z * raw[t * 6 + 2] * inv;
        m.w = z * raw[t * 6 + 3] * inv;
        means4[t] = m;
        invci[t]  = 1.f / fmaxf(cnti, 1.f);
    }
    __syncthreads();

    // ---- phase 2: l_agg from register-held emb (zero global loads) ----
    float acc = procQ2(pk0, xq[0], means4, invci)
              + procQ2(pk1, xq[1], means4, invci)
              + procQ2(pk2, xq[2], means4, invci)
              + procQ2(pk3, xq[3], means4, invci);
    float v = acc * (1.f / 32.f);

    if (bx == 0) {                         // l_dis + l_reg once per batch
        float disp = 0.f;
        #pragma unroll
        for (int p = t; p < 1024; p += 256) {
            int i = p >> 5, j = p & 31;
            if (i != j) {
                float4 mi = means4[i + 1], mj = means4[j + 1];
                float d0 = mi.x - mj.x, d1 = mi.y - mj.y;
                float d2 = mi.z - mj.z, d3 = mi.w - mj.w;
                float pd = sqrtf(d0 * d0 + d1 * d1 + d2 * d2 + d3 * d3);
                float u = fmaxf(3.0f - pd, 0.f);
                disp += __logf(u * u + 1.f);
            }
        }
        v += disp * (1.f / 992.f);         // 32*31
        if (t >= 1 && t < NLAB) {
            float4 m = means4[t];
            float n2 = m.x * m.x + m.y * m.y + m.z * m.z + m.w * m.w;
            v += __logf(sqrtf(n2) + 1.f) * (0.001f / 33.f);
        }
    }

    v = wave_sum(v);
    if ((t & 63) == 0) red[t >> 6] = v;
    __syncthreads();
    if (t == 0)
        atomAddF(out, (red[0] + red[1] + red[2] + red[3]) * (1.f / BATCH));
}

extern "C" void kernel_launch(void* const* d_in, const int* in_sizes, int n_in,
                              void* d_out, int out_size, void* d_ws, size_t ws_size,
                              hipStream_t stream) {
    const float* emb   = (const float*)d_in[0];
    const int*   inst  = (const int*)  d_in[1];
    const float* kern  = (const float*)d_in[2];
    const float* tmask = (const float*)d_in[3];
    float* ws  = (float*)d_ws;
    float* out = (float*)d_out;

    // zero barrier counter + AWS bins + out via memset nodes (DMA)
    hipMemsetAsync((void*)ws, 0, (AWS_OFF + BATCH * 208) * sizeof(float), stream);
    hipMemsetAsync(d_out, 0, sizeof(float), stream);

    fused<<<dim3(GXB, BATCH), 256, 0, stream>>>(emb, inst, kern, tmask, ws, out);
}

// Round 13
// 178.322 us; speedup vs baseline: 1.4474x; 1.4474x over previous
//
#include <hip/hip_runtime.h>
#include <math.h>

#define HW    409600      // 640*640
#define HW4   102400      // float4-quads per (batch,dim)
#define BATCH 8
#define NLAB  33
#define GXB   400         // blocks per batch; 1 quad (4 px) per thread
#define NREP  16          // LDS bin replicas (per 4-lane cluster)
#define RS    201         // replica stride
// ws float-offset layout:
#define AWS_OFF   1344                     // [8][208] global atomic bins
#define LABS_OFF_F 3008                    // u32 [8][HW4] packed labels
#define NEED_LABS  ((size_t)LABS_OFF_F * 4 + (size_t)BATCH * HW4 * 4)

// Native fp32 atomic add (ds_add_f32 / global_atomic_add_f32) — avoids the
// CAS-loop expansion hipcc emits for atomicAdd(float*) without
// -munsafe-fp-atomics.
__device__ __forceinline__ void atomAddF(float* p, float v) {
    unsafeAtomicAdd(p, v);
}

__device__ __forceinline__ float getc(const float4& v, int e) {
    return (e == 0) ? v.x : (e == 1) ? v.y : (e == 2) ? v.z : v.w;
}
__device__ __forceinline__ float wave_sum(float v) {
    #pragma unroll
    for (int o = 32; o > 0; o >>= 1) v += __shfl_xor(v, o);
    return v;
}

// ---------------- pass1: 1 quad/thread, max-occupancy ----------------
__device__ __forceinline__ void acc1(int l, bool k,
                                     float x0, float x1, float x2, float x3,
                                     float* mb) {
    if (l) {
        float* bb = mb + l * 6;
        // packed counts: cnt_k hi16, cnt_i lo16 (per-block <= 1024 px, no carry)
        atomicAdd((unsigned*)(bb + 4), k ? 0x10001u : 1u);   // ds_add_u32, native
        if (k) {
            atomAddF(bb + 0, x0);
            atomAddF(bb + 1, x1);
            atomAddF(bb + 2, x2);
            atomAddF(bb + 3, x3);
        }
    }
}

__global__ __launch_bounds__(256, 8) void pass1(const float* __restrict__ emb,
                                                const int*   __restrict__ inst,
                                                const float* __restrict__ kern,
                                                const float* __restrict__ tmask,
                                                float*       __restrict__ ws,
                                                unsigned*    __restrict__ labs) {
    __shared__ float bins[NREP][RS];
    const int t = threadIdx.x, bx = blockIdx.x, b = blockIdx.y;
    float* mb = bins[(t >> 2) & (NREP - 1)];   // 4 lanes per replica

    const size_t  base  = (size_t)b * HW;
    const float4* emb4  = (const float4*)(emb + base * 4);
    const int4*   inst4 = (const int4*)(inst + base);
    const float4* kern4 = (const float4*)(kern + base);
    const float4* tm4   = (const float4*)(tmask + base);
    const int g = bx * 256 + t;                // one quad per thread

    // all 7 loads upfront; LDS zeroing + barrier covers the latency
    int4   iv = inst4[g];
    float4 tv = tm4[g];
    float4 kv = kern4[g];
    float4 x0 = emb4[g];
    float4 x1 = emb4[g + HW4];
    float4 x2 = emb4[g + 2 * HW4];
    float4 x3 = emb4[g + 3 * HW4];

    for (int i = t; i < NREP * RS; i += 256) (&bins[0][0])[i] = 0.f;
    __syncthreads();

    int l0 = (tv.x > 0.5f) ? iv.x : 0;
    int l1 = (tv.y > 0.5f) ? iv.y : 0;
    int l2 = (tv.z > 0.5f) ? iv.z : 0;
    int l3 = (tv.w > 0.5f) ? iv.w : 0;
    if (labs)
        labs[(size_t)b * HW4 + g] = (unsigned)l0 | ((unsigned)l1 << 8) |
                                    ((unsigned)l2 << 16) | ((unsigned)l3 << 24);
    acc1(l0, kv.x > 0.5f, x0.x, x1.x, x2.x, x3.x, mb);
    acc1(l1, kv.y > 0.5f, x0.y, x1.y, x2.y, x3.y, mb);
    acc1(l2, kv.z > 0.5f, x0.z, x1.z, x2.z, x3.z, mb);
    acc1(l3, kv.w > 0.5f, x0.w, x1.w, x2.w, x3.w, mb);
    __syncthreads();

    if (t < NLAB * 6) {
        const int l = t / 6, k = t - l * 6;
        float v;
        if (k >= 4) {
            unsigned s = 0;
            #pragma unroll
            for (int r = 0; r < NREP; ++r)
                s += ((const unsigned*)bins[r])[l * 6 + 4];
            v = (k == 4) ? (float)(s >> 16) : (float)(s & 0xffffu);
        } else {
            float fs = 0.f;
            #pragma unroll
            for (int r = 0; r < NREP; ++r) fs += bins[r][l * 6 + k];
            v = fs;
        }
        if (v != 0.f) atomAddF(ws + AWS_OFF + b * 208 + t, v);   // native global atomic
    }
}

// ---------------- pass2: 1 quad/thread; bx==0 adds l_dis+l_reg ----------------
template<bool USE_LABS>
__global__ __launch_bounds__(256, 8) void pass2(const float* __restrict__ emb,
                                                const int*   __restrict__ inst,
                                                const float* __restrict__ tmask,
                                                const float* __restrict__ ws,
                                                const unsigned* __restrict__ labs,
                                                float*       __restrict__ out) {
    __shared__ float  raw[200];
    __shared__ float4 means4[NLAB];
    __shared__ float  invci[NLAB];
    __shared__ float  red[4];
    const int t = threadIdx.x, bx = blockIdx.x, b = blockIdx.y;

    const size_t  base  = (size_t)b * HW;
    const float4* emb4  = (const float4*)(emb + base * 4);
    const int4*   inst4 = (const int4*)(inst + base);
    const float4* tm4   = (const float4*)(tmask + base);
    const int g = bx * 256 + t;

    // loads upfront; means prologue covers latency
    unsigned pk;
    int4 iv; float4 tv;
    if (USE_LABS) {
        pk = labs[(size_t)b * HW4 + g];
    } else {
        iv = inst4[g];
        tv = tm4[g];
    }
    float4 x0 = emb4[g];
    float4 x1 = emb4[g + HW4];
    float4 x2 = emb4[g + 2 * HW4];
    float4 x3 = emb4[g + 3 * HW4];

    if (t < NLAB * 6) raw[t] = ws[AWS_OFF + b * 208 + t];
    __syncthreads();
    if (t < NLAB) {
        float cntk = raw[t * 6 + 4], cnti = raw[t * 6 + 5];
        float inv = 1.f / fmaxf(cntk, 1.f);
        float z = (t == 0) ? 0.f : 1.f;
        float4 m;
        m.x = z * raw[t * 6 + 0] * inv;
        m.y = z * raw[t * 6 + 1] * inv;
        m.z = z * raw[t * 6 + 2] * inv;
        m.w = z * raw[t * 6 + 3] * inv;
        means4[t] = m;
        invci[t]  = 1.f / fmaxf(cnti, 1.f);
    }
    __syncthreads();

    if (!USE_LABS) {
        pk = (unsigned)((tv.x > 0.5f) ? iv.x : 0)        |
             ((unsigned)((tv.y > 0.5f) ? iv.y : 0) << 8) |
             ((unsigned)((tv.z > 0.5f) ? iv.z : 0) << 16)|
             ((unsigned)((tv.w > 0.5f) ? iv.w : 0) << 24);
    }
    float acc = 0.f;
    #pragma unroll
    for (int e = 0; e < 4; ++e) {
        int l = (pk >> (8 * e)) & 255;
        if (l) {
            float4 m = means4[l];
            float d0 = getc(x0, e) - m.x, d1 = getc(x1, e) - m.y;
            float d2 = getc(x2, e) - m.z, d3 = getc(x3, e) - m.w;
            float dist = sqrtf(d0 * d0 + d1 * d1 + d2 * d2 + d3 * d3);
            float u = fmaxf(dist - 0.5f, 0.f);
            acc += __logf(u * u + 1.f) * invci[l];
        }
    }
    float v = acc * (1.f / 32.f);                 // l_agg contribution

    if (bx == 0) {                                // l_dis + l_reg once per batch
        float disp = 0.f;
        #pragma unroll
        for (int p = t; p < 1024; p += 256) {
            int i = p >> 5, j = p & 31;
            if (i != j) {
                float4 mi = means4[i + 1], mj = means4[j + 1];
                float d0 = mi.x - mj.x, d1 = mi.y - mj.y;
                float d2 = mi.z - mj.z, d3 = mi.w - mj.w;
                float pd = sqrtf(d0 * d0 + d1 * d1 + d2 * d2 + d3 * d3);
                float u = fmaxf(3.0f - pd, 0.f);
                disp += __logf(u * u + 1.f);
            }
        }
        v += disp * (1.f / 992.f);                // 32*31
        if (t >= 1 && t < NLAB) {
            float4 m = means4[t];
            float n2 = m.x * m.x + m.y * m.y + m.z * m.z + m.w * m.w;
            v += __logf(sqrtf(n2) + 1.f) * (0.001f / 33.f);
        }
    }

    v = wave_sum(v);
    if ((t & 63) == 0) red[t >> 6] = v;
    __syncthreads();
    if (t == 0)
        atomAddF(out, (red[0] + red[1] + red[2] + red[3]) * (1.f / BATCH));
}

extern "C" void kernel_launch(void* const* d_in, const int* in_sizes, int n_in,
                              void* d_out, int out_size, void* d_ws, size_t ws_size,
                              hipStream_t stream) {
    const float* emb   = (const float*)d_in[0];
    const int*   inst  = (const int*)  d_in[1];
    const float* kern  = (const float*)d_in[2];
    const float* tmask = (const float*)d_in[3];
    float* ws  = (float*)d_ws;
    float* out = (float*)d_out;

    const bool use_labs = ws_size >= NEED_LABS;
    unsigned* labs = use_labs ? (unsigned*)(ws + LABS_OFF_F) : nullptr;

    // zero AWS bins + out via memset nodes (DMA)
    hipMemsetAsync((void*)(ws + AWS_OFF), 0, BATCH * 208 * sizeof(float), stream);
    hipMemsetAsync(d_out, 0, sizeof(float), stream);

    dim3 grid(GXB, BATCH);
    pass1<<<grid, 256, 0, stream>>>(emb, inst, kern, tmask, ws, labs);
    if (use_labs) pass2<true ><<<grid, 256, 0, stream>>>(emb, inst, tmask, ws, labs, out);
    else          pass2<false><<<grid, 256, 0, stream>>>(emb, inst, tmask, ws, nullptr, out);
}

// Round 15
// 144.174 us; speedup vs baseline: 1.7902x; 1.2369x over previous
//
#include <hip/hip_runtime.h>
#include <math.h>

#define HW    409600      // 640*640
#define HW4   102400      // float4-quads per (batch,dim)
#define BATCH 8
#define NLAB  33
#define GXB   100         // pass1/pass2 blocks per batch; 4 quads/thread
#define NREP  16          // LDS bin replicas (per 4-lane cluster)
#define RS    201         // replica stride
// ws float-offset layout:
#define AWS_OFF   1344                     // [8][208] global atomic bins
#define LABS_OFF_F 3008                    // u32 [8][HW4] packed labels
#define NEED_LABS  ((size_t)LABS_OFF_F * 4 + (size_t)BATCH * HW4 * 4)

#if defined(__has_builtin) && __has_builtin(__builtin_amdgcn_sched_barrier)
#define SCHED_PIN() __builtin_amdgcn_sched_barrier(0)
#else
#define SCHED_PIN()
#endif

// Native fp32 atomic add (ds_add_f32 / global_atomic_add_f32) — avoids the
// CAS-loop expansion hipcc emits for atomicAdd(float*) without
// -munsafe-fp-atomics. Values here are normal-range; denorm flush is moot.
__device__ __forceinline__ void atomAddF(float* p, float v) {
    unsafeAtomicAdd(p, v);
}

__device__ __forceinline__ float getc(const float4& v, int e) {
    return (e == 0) ? v.x : (e == 1) ? v.y : (e == 2) ? v.z : v.w;
}
__device__ __forceinline__ float wave_sum(float v) {
    #pragma unroll
    for (int o = 32; o > 0; o >>= 1) v += __shfl_xor(v, o);
    return v;
}

// ---------------- pass1 ----------------
struct Quad { int4 iv; float4 tv, kv, x0, x1, x2, x3; };

__device__ __forceinline__ void loadQ(Quad& q, const int4* inst4, const float4* tm4,
                                      const float4* kern4, const float4* emb4, int g) {
    q.iv = inst4[g];
    q.tv = tm4[g];
    q.kv = kern4[g];
    q.x0 = emb4[g];
    q.x1 = emb4[g + HW4];
    q.x2 = emb4[g + 2 * HW4];
    q.x3 = emb4[g + 3 * HW4];
}

__device__ __forceinline__ void acc1(int l, bool k,
                                     float x0, float x1, float x2, float x3,
                                     float* mb) {
    if (l) {
        float* bb = mb + l * 6;
        // packed counts: cnt_k in high 16, cnt_i in low 16 (per-block <= 4096,
        // so replica sums cannot carry into bit 16)
        atomicAdd((unsigned*)(bb + 4), k ? 0x10001u : 1u);   // ds_add_u32, native
        if (k) {
            atomAddF(bb + 0, x0);
            atomAddF(bb + 1, x1);
            atomAddF(bb + 2, x2);
            atomAddF(bb + 3, x3);
        }
    }
}

__device__ __forceinline__ void procQ(const Quad& q, float* mb,
                                      unsigned* labs, size_t labidx) {
    int l0 = (q.tv.x > 0.5f) ? q.iv.x : 0;
    int l1 = (q.tv.y > 0.5f) ? q.iv.y : 0;
    int l2 = (q.tv.z > 0.5f) ? q.iv.z : 0;
    int l3 = (q.tv.w > 0.5f) ? q.iv.w : 0;
    if (labs)
        labs[labidx] = (unsigned)l0 | ((unsigned)l1 << 8) |
                       ((unsigned)l2 << 16) | ((unsigned)l3 << 24);
    acc1(l0, q.kv.x > 0.5f, q.x0.x, q.x1.x, q.x2.x, q.x3.x, mb);
    acc1(l1, q.kv.y > 0.5f, q.x0.y, q.x1.y, q.x2.y, q.x3.y, mb);
    acc1(l2, q.kv.z > 0.5f, q.x0.z, q.x1.z, q.x2.z, q.x3.z, mb);
    acc1(l3, q.kv.w > 0.5f, q.x0.w, q.x1.w, q.x2.w, q.x3.w, mb);
}

__global__ __launch_bounds__(256, 4) void pass1(const float* __restrict__ emb,
                                                const int*   __restrict__ inst,
                                                const float* __restrict__ kern,
                                                const float* __restrict__ tmask,
                                                float*       __restrict__ ws,
                                                unsigned*    __restrict__ labs) {
    __shared__ float bins[NREP][RS];
    const int t = threadIdx.x, bx = blockIdx.x, b = blockIdx.y;
    float* mb = bins[(t >> 2) & (NREP - 1)];   // 4 lanes per replica

    const size_t  base  = (size_t)b * HW;
    const float4* emb4  = (const float4*)(emb + base * 4);
    const int4*   inst4 = (const int4*)(inst + base);
    const float4* kern4 = (const float4*)(kern + base);
    const float4* tm4   = (const float4*)(tmask + base);
    const int q0 = bx * 1024 + t;                 // chunk c: q0 + c*256
    const size_t lb = (size_t)b * HW4;

    Quad c0, c1;
    loadQ(c0, inst4, tm4, kern4, emb4, q0);
    loadQ(c1, inst4, tm4, kern4, emb4, q0 + 256);
    SCHED_PIN();

    for (int i = t; i < NREP * RS; i += 256) (&bins[0][0])[i] = 0.f;
    __syncthreads();

    procQ(c0, mb, labs, lb + q0);
    loadQ(c0, inst4, tm4, kern4, emb4, q0 + 512);
    SCHED_PIN();
    procQ(c1, mb, labs, lb + q0 + 256);
    loadQ(c1, inst4, tm4, kern4, emb4, q0 + 768);
    SCHED_PIN();
    procQ(c0, mb, labs, lb + q0 + 512);
    procQ(c1, mb, labs, lb + q0 + 768);
    __syncthreads();

    if (t < NLAB * 6) {
        const int l = t / 6, k = t - l * 6;
        float v;
        if (k >= 4) {
            unsigned s = 0;
            #pragma unroll
            for (int r = 0; r < NREP; ++r)
                s += ((const unsigned*)bins[r])[l * 6 + 4];
            v = (k == 4) ? (float)(s >> 16) : (float)(s & 0xffffu);
        } else {
            float fs = 0.f;
            #pragma unroll
            for (int r = 0; r < NREP; ++r) fs += bins[r][l * 6 + k];
            v = fs;
        }
        if (v != 0.f) atomAddF(ws + AWS_OFF + b * 208 + t, v);   // native global atomic
    }
}

// ---------------- pass2: per-block means prologue + l_agg; bx==0 adds l_dis+l_reg ----
struct Quad2 { unsigned pk; int4 iv; float4 tv, x0, x1, x2, x3; };

template<bool USE_LABS>
__device__ __forceinline__ void loadQ2(Quad2& q, const unsigned* labs, size_t lb,
                                       const int4* inst4, const float4* tm4,
                                       const float4* emb4, int g) {
    if (USE_LABS) {
        q.pk = labs[lb + g];
    } else {
        q.iv = inst4[g];
        q.tv = tm4[g];
    }
    q.x0 = emb4[g];
    q.x1 = emb4[g + HW4];
    q.x2 = emb4[g + 2 * HW4];
    q.x3 = emb4[g + 3 * HW4];
}

template<bool USE_LABS>
__device__ __forceinline__ float procQ2(const Quad2& q, const float4* means4,
                                        const float* invci) {
    unsigned pk;
    if (USE_LABS) {
        pk = q.pk;
    } else {
        pk = (unsigned)((q.tv.x > 0.5f) ? q.iv.x : 0)        |
             ((unsigned)((q.tv.y > 0.5f) ? q.iv.y : 0) << 8) |
             ((unsigned)((q.tv.z > 0.5f) ? q.iv.z : 0) << 16)|
             ((unsigned)((q.tv.w > 0.5f) ? q.iv.w : 0) << 24);
    }
    float acc = 0.f;
    #pragma unroll
    for (int e = 0; e < 4; ++e) {
        int l = (pk >> (8 * e)) & 255;
        if (l) {
            float4 m = means4[l];
            float d0 = getc(q.x0, e) - m.x, d1 = getc(q.x1, e) - m.y;
            float d2 = getc(q.x2, e) - m.z, d3 = getc(q.x3, e) - m.w;
            float dist = sqrtf(d0 * d0 + d1 * d1 + d2 * d2 + d3 * d3);
            float u = fmaxf(dist - 0.5f, 0.f);
            acc += __logf(u * u + 1.f) * invci[l];
        }
    }
    return acc;
}

template<bool USE_LABS>
__global__ __launch_bounds__(256, 4) void pass2(const float* __restrict__ emb,
                                                const int*   __restrict__ inst,
                                                const float* __restrict__ tmask,
                                                const float* __restrict__ ws,
                                                const unsigned* __restrict__ labs,
                                                float*       __restrict__ out) {
    __shared__ float  raw[200];
    __shared__ float4 means4[NLAB];
    __shared__ float  invci[NLAB];
    __shared__ float  red[4];
    const int t = threadIdx.x, bx = blockIdx.x, b = blockIdx.y;

    const size_t  base  = (size_t)b * HW;
    const float4* emb4  = (const float4*)(emb + base * 4);
    const int4*   inst4 = (const int4*)(inst + base);
    const float4* tm4   = (const float4*)(tmask + base);
    const int q0 = bx * 1024 + t;
    const size_t lb = (size_t)b * HW4;

    Quad2 c0, c1;
    loadQ2<USE_LABS>(c0, labs, lb, inst4, tm4, emb4, q0);
    loadQ2<USE_LABS>(c1, labs, lb, inst4, tm4, emb4, q0 + 256);
    SCHED_PIN();

    // --- per-block means/invci from AWS bins (L2/L3-resident, ~200 loads) ---
    if (t < NLAB * 6) raw[t] = ws[AWS_OFF + b * 208 + t];
    __syncthreads();
    if (t < NLAB) {
        float cntk = raw[t * 6 + 4], cnti = raw[t * 6 + 5];
        float inv = 1.f / fmaxf(cntk, 1.f);
        float z = (t == 0) ? 0.f : 1.f;
        float4 m;
        m.x = z * raw[t * 6 + 0] * inv;
        m.y = z * raw[t * 6 + 1] * inv;
        m.z = z * raw[t * 6 + 2] * inv;
        m.w = z * raw[t * 6 + 3] * inv;
        means4[t] = m;
        invci[t]  = 1.f / fmaxf(cnti, 1.f);
    }
    __syncthreads();

    float acc = procQ2<USE_LABS>(c0, means4, invci);
    loadQ2<USE_LABS>(c0, labs, lb, inst4, tm4, emb4, q0 + 512);
    SCHED_PIN();
    acc += procQ2<USE_LABS>(c1, means4, invci);
    loadQ2<USE_LABS>(c1, labs, lb, inst4, tm4, emb4, q0 + 768);
    SCHED_PIN();
    acc += procQ2<USE_LABS>(c0, means4, invci);
    acc += procQ2<USE_LABS>(c1, means4, invci);

    float v = acc * (1.f / 32.f);                 // l_agg contribution

    if (bx == 0) {                                // l_dis + l_reg once per batch
        float disp = 0.f;
        #pragma unroll
        for (int p = t; p < 1024; p += 256) {
            int i = p >> 5, j = p & 31;
            if (i != j) {
                float4 mi = means4[i + 1], mj = means4[j + 1];
                float d0 = mi.x - mj.x, d1 = mi.y - mj.y;
                float d2 = mi.z - mj.z, d3 = mi.w - mj.w;
                float pd = sqrtf(d0 * d0 + d1 * d1 + d2 * d2 + d3 * d3);
                float u = fmaxf(3.0f - pd, 0.f);
                disp += __logf(u * u + 1.f);
            }
        }
        v += disp * (1.f / 992.f);                // 32*31
        if (t >= 1 && t < NLAB) {
            float4 m = means4[t];
            float n2 = m.x * m.x + m.y * m.y + m.z * m.z + m.w * m.w;
            v += __logf(sqrtf(n2) + 1.f) * (0.001f / 33.f);
        }
    }

    v = wave_sum(v);
    if ((t & 63) == 0) red[t >> 6] = v;
    __syncthreads();
    if (t == 0)
        atomAddF(out, (red[0] + red[1] + red[2] + red[3]) * (1.f / BATCH));
}

extern "C" void kernel_launch(void* const* d_in, const int* in_sizes, int n_in,
                              void* d_out, int out_size, void* d_ws, size_t ws_size,
                              hipStream_t stream) {
    const float* emb   = (const float*)d_in[0];
    const int*   inst  = (const int*)  d_in[1];
    const float* kern  = (const float*)d_in[2];
    const float* tmask = (const float*)d_in[3];
    float* ws  = (float*)d_ws;
    float* out = (float*)d_out;

    const bool use_labs = ws_size >= NEED_LABS;
    unsigned* labs = use_labs ? (unsigned*)(ws + LABS_OFF_F) : nullptr;

    // zero AWS bins + out via memset nodes (DMA; no init kernel)
    hipMemsetAsync((void*)(ws + AWS_OFF), 0, BATCH * 208 * sizeof(float), stream);
    hipMemsetAsync(d_out, 0, sizeof(float), stream);

    dim3 grid(GXB, BATCH);
    pass1<<<grid, 256, 0, stream>>>(emb, inst, kern, tmask, ws, labs);
    if (use_labs) pass2<true ><<<grid, 256, 0, stream>>>(emb, inst, tmask, ws, labs, out);
    else          pass2<false><<<grid, 256, 0, stream>>>(emb, inst, tmask, ws, nullptr, out);
}

// Round 16
// 141.459 us; speedup vs baseline: 1.8245x; 1.0192x over previous
//
#include <hip/hip_runtime.h>
#include <math.h>

#define HW    409600      // 640*640
#define HW4   102400      // float4-quads per (batch,dim)
#define BATCH 8
#define NLAB  33
#define GXB   100         // pass1/pass2 blocks per batch; 4 quads/thread
#define NREP  16          // LDS bin replicas (per 4-lane cluster)
#define RS    201         // replica stride
// ws float-offset layout:
#define AWS_OFF   1344                     // [8][208] global atomic bins
#define LABS_OFF_F 3008                    // u32 [8][HW4] packed labels
#define NEED_LABS  ((size_t)LABS_OFF_F * 4 + (size_t)BATCH * HW4 * 4)

#if defined(__has_builtin) && __has_builtin(__builtin_amdgcn_sched_barrier)
#define SCHED_PIN() __builtin_amdgcn_sched_barrier(0)
#else
#define SCHED_PIN()
#endif

// Native fp32 atomic add (ds_add_f32 / global_atomic_add_f32) — avoids the
// CAS-loop expansion hipcc emits for atomicAdd(float*) without
// -munsafe-fp-atomics. Values here are normal-range; denorm flush is moot.
__device__ __forceinline__ void atomAddF(float* p, float v) {
    unsafeAtomicAdd(p, v);
}

__device__ __forceinline__ float getc(const float4& v, int e) {
    return (e == 0) ? v.x : (e == 1) ? v.y : (e == 2) ? v.z : v.w;
}
__device__ __forceinline__ float wave_sum(float v) {
    #pragma unroll
    for (int o = 32; o > 0; o >>= 1) v += __shfl_xor(v, o);
    return v;
}

// ---------------- pass1 ----------------
struct Quad { int4 iv; float4 tv, kv, x0, x1, x2, x3; };

__device__ __forceinline__ void loadQ(Quad& q, const int4* inst4, const float4* tm4,
                                      const float4* kern4, const float4* emb4, int g) {
    q.iv = inst4[g];
    q.tv = tm4[g];
    q.kv = kern4[g];
    q.x0 = emb4[g];
    q.x1 = emb4[g + HW4];
    q.x2 = emb4[g + 2 * HW4];
    q.x3 = emb4[g + 3 * HW4];
}

__device__ __forceinline__ void acc1(int l, bool k,
                                     float x0, float x1, float x2, float x3,
                                     float* mb) {
    if (l) {
        float* bb = mb + l * 6;
        // packed counts: cnt_k in high 16, cnt_i in low 16 (per-block <= 4096,
        // so replica sums cannot carry into bit 16)
        atomicAdd((unsigned*)(bb + 4), k ? 0x10001u : 1u);   // ds_add_u32, native
        if (k) {
            atomAddF(bb + 0, x0);
            atomAddF(bb + 1, x1);
            atomAddF(bb + 2, x2);
            atomAddF(bb + 3, x3);
        }
    }
}

__device__ __forceinline__ void procQ(const Quad& q, float* mb,
                                      unsigned* labs, size_t labidx) {
    int l0 = (q.tv.x > 0.5f) ? q.iv.x : 0;
    int l1 = (q.tv.y > 0.5f) ? q.iv.y : 0;
    int l2 = (q.tv.z > 0.5f) ? q.iv.z : 0;
    int l3 = (q.tv.w > 0.5f) ? q.iv.w : 0;
    if (labs)
        labs[labidx] = (unsigned)l0 | ((unsigned)l1 << 8) |
                       ((unsigned)l2 << 16) | ((unsigned)l3 << 24);
    acc1(l0, q.kv.x > 0.5f, q.x0.x, q.x1.x, q.x2.x, q.x3.x, mb);
    acc1(l1, q.kv.y > 0.5f, q.x0.y, q.x1.y, q.x2.y, q.x3.y, mb);
    acc1(l2, q.kv.z > 0.5f, q.x0.z, q.x1.z, q.x2.z, q.x3.z, mb);
    acc1(l3, q.kv.w > 0.5f, q.x0.w, q.x1.w, q.x2.w, q.x3.w, mb);
}

__global__ __launch_bounds__(256, 4) void pass1(const float* __restrict__ emb,
                                                const int*   __restrict__ inst,
                                                const float* __restrict__ kern,
                                                const float* __restrict__ tmask,
                                                float*       __restrict__ ws,
                                                unsigned*    __restrict__ labs,
                                                float*       __restrict__ out) {
    __shared__ float bins[NREP][RS];
    const int t = threadIdx.x, bx = blockIdx.x, b = blockIdx.y;
    float* mb = bins[(t >> 2) & (NREP - 1)];   // 4 lanes per replica

    // zero the output accumulator here (replaces a dedicated memset dispatch;
    // kernel boundary orders this before pass2's atomicAdds)
    if (bx == 0 && b == 0 && t == 0) out[0] = 0.f;

    const size_t  base  = (size_t)b * HW;
    const float4* emb4  = (const float4*)(emb + base * 4);
    const int4*   inst4 = (const int4*)(inst + base);
    const float4* kern4 = (const float4*)(kern + base);
    const float4* tm4   = (const float4*)(tmask + base);
    const int q0 = bx * 1024 + t;                 // chunk c: q0 + c*256
    const size_t lb = (size_t)b * HW4;

    Quad c0, c1;
    loadQ(c0, inst4, tm4, kern4, emb4, q0);
    loadQ(c1, inst4, tm4, kern4, emb4, q0 + 256);
    SCHED_PIN();

    for (int i = t; i < NREP * RS; i += 256) (&bins[0][0])[i] = 0.f;
    __syncthreads();

    procQ(c0, mb, labs, lb + q0);
    loadQ(c0, inst4, tm4, kern4, emb4, q0 + 512);
    SCHED_PIN();
    procQ(c1, mb, labs, lb + q0 + 256);
    loadQ(c1, inst4, tm4, kern4, emb4, q0 + 768);
    SCHED_PIN();
    procQ(c0, mb, labs, lb + q0 + 512);
    procQ(c1, mb, labs, lb + q0 + 768);
    __syncthreads();

    if (t < NLAB * 6) {
        const int l = t / 6, k = t - l * 6;
        float v;
        if (k >= 4) {
            unsigned s = 0;
            #pragma unroll
            for (int r = 0; r < NREP; ++r)
                s += ((const unsigned*)bins[r])[l * 6 + 4];
            v = (k == 4) ? (float)(s >> 16) : (float)(s & 0xffffu);
        } else {
            float fs = 0.f;
            #pragma unroll
            for (int r = 0; r < NREP; ++r) fs += bins[r][l * 6 + k];
            v = fs;
        }
        if (v != 0.f) atomAddF(ws + AWS_OFF + b * 208 + t, v);   // native global atomic
    }
}

// ---------------- pass2: per-block means prologue + l_agg; bx==0 adds l_dis+l_reg ----
struct Quad2 { unsigned pk; int4 iv; float4 tv, x0, x1, x2, x3; };

template<bool USE_LABS>
__device__ __forceinline__ void loadQ2(Quad2& q, const unsigned* labs, size_t lb,
                                       const int4* inst4, const float4* tm4,
                                       const float4* emb4, int g) {
    if (USE_LABS) {
        q.pk = labs[lb + g];
    } else {
        q.iv = inst4[g];
        q.tv = tm4[g];
    }
    q.x0 = emb4[g];
    q.x1 = emb4[g + HW4];
    q.x2 = emb4[g + 2 * HW4];
    q.x3 = emb4[g + 3 * HW4];
}

template<bool USE_LABS>
__device__ __forceinline__ float procQ2(const Quad2& q, const float4* means4,
                                        const float* invci) {
    unsigned pk;
    if (USE_LABS) {
        pk = q.pk;
    } else {
        pk = (unsigned)((q.tv.x > 0.5f) ? q.iv.x : 0)        |
             ((unsigned)((q.tv.y > 0.5f) ? q.iv.y : 0) << 8) |
             ((unsigned)((q.tv.z > 0.5f) ? q.iv.z : 0) << 16)|
             ((unsigned)((q.tv.w > 0.5f) ? q.iv.w : 0) << 24);
    }
    float acc = 0.f;
    #pragma unroll
    for (int e = 0; e < 4; ++e) {
        int l = (pk >> (8 * e)) & 255;
        if (l) {
            float4 m = means4[l];
            float d0 = getc(q.x0, e) - m.x, d1 = getc(q.x1, e) - m.y;
            float d2 = getc(q.x2, e) - m.z, d3 = getc(q.x3, e) - m.w;
            float dist = sqrtf(d0 * d0 + d1 * d1 + d2 * d2 + d3 * d3);
            float u = fmaxf(dist - 0.5f, 0.f);
            acc += __logf(u * u + 1.f) * invci[l];
        }
    }
    return acc;
}

template<bool USE_LABS>
__global__ __launch_bounds__(256, 4) void pass2(const float* __restrict__ emb,
                                                const int*   __restrict__ inst,
                                                const float* __restrict__ tmask,
                                                const float* __restrict__ ws,
                                                const unsigned* __restrict__ labs,
                                                float*       __restrict__ out) {
    __shared__ float  raw[200];
    __shared__ float4 means4[NLAB];
    __shared__ float  invci[NLAB];
    __shared__ float  red[4];
    const int t = threadIdx.x, bx = blockIdx.x, b = blockIdx.y;

    const size_t  base  = (size_t)b * HW;
    const float4* emb4  = (const float4*)(emb + base * 4);
    const int4*   inst4 = (const int4*)(inst + base);
    const float4* tm4   = (const float4*)(tmask + base);
    const int q0 = bx * 1024 + t;
    const size_t lb = (size_t)b * HW4;

    Quad2 c0, c1;
    loadQ2<USE_LABS>(c0, labs, lb, inst4, tm4, emb4, q0);
    loadQ2<USE_LABS>(c1, labs, lb, inst4, tm4, emb4, q0 + 256);
    SCHED_PIN();

    // --- per-block means/invci from AWS bins (L2/L3-resident, ~200 loads) ---
    if (t < NLAB * 6) raw[t] = ws[AWS_OFF + b * 208 + t];
    __syncthreads();
    if (t < NLAB) {
        float cntk = raw[t * 6 + 4], cnti = raw[t * 6 + 5];
        float inv = 1.f / fmaxf(cntk, 1.f);
        float z = (t == 0) ? 0.f : 1.f;
        float4 m;
        m.x = z * raw[t * 6 + 0] * inv;
        m.y = z * raw[t * 6 + 1] * inv;
        m.z = z * raw[t * 6 + 2] * inv;
        m.w = z * raw[t * 6 + 3] * inv;
        means4[t] = m;
        invci[t]  = 1.f / fmaxf(cnti, 1.f);
    }
    __syncthreads();

    float acc = procQ2<USE_LABS>(c0, means4, invci);
    loadQ2<USE_LABS>(c0, labs, lb, inst4, tm4, emb4, q0 + 512);
    SCHED_PIN();
    acc += procQ2<USE_LABS>(c1, means4, invci);
    loadQ2<USE_LABS>(c1, labs, lb, inst4, tm4, emb4, q0 + 768);
    SCHED_PIN();
    acc += procQ2<USE_LABS>(c0, means4, invci);
    acc += procQ2<USE_LABS>(c1, means4, invci);

    float v = acc * (1.f / 32.f);                 // l_agg contribution

    if (bx == 0) {                                // l_dis + l_reg once per batch
        float disp = 0.f;
        #pragma unroll
        for (int p = t; p < 1024; p += 256) {
            int i = p >> 5, j = p & 31;
            if (i != j) {
                float4 mi = means4[i + 1], mj = means4[j + 1];
                float d0 = mi.x - mj.x, d1 = mi.y - mj.y;
                float d2 = mi.z - mj.z, d3 = mi.w - mj.w;
                float pd = sqrtf(d0 * d0 + d1 * d1 + d2 * d2 + d3 * d3);
                float u = fmaxf(3.0f - pd, 0.f);
                disp += __logf(u * u + 1.f);
            }
        }
        v += disp * (1.f / 992.f);                // 32*31
        if (t >= 1 && t < NLAB) {
            float4 m = means4[t];
            float n2 = m.x * m.x + m.y * m.y + m.z * m.z + m.w * m.w;
            v += __logf(sqrtf(n2) + 1.f) * (0.001f / 33.f);
        }
    }

    v = wave_sum(v);
    if ((t & 63) == 0) red[t >> 6] = v;
    __syncthreads();
    if (t == 0)
        atomAddF(out, (red[0] + red[1] + red[2] + red[3]) * (1.f / BATCH));
}

extern "C" void kernel_launch(void* const* d_in, const int* in_sizes, int n_in,
                              void* d_out, int out_size, void* d_ws, size_t ws_size,
                              hipStream_t stream) {
    const float* emb   = (const float*)d_in[0];
    const int*   inst  = (const int*)  d_in[1];
    const float* kern  = (const float*)d_in[2];
    const float* tmask = (const float*)d_in[3];
    float* ws  = (float*)d_ws;
    float* out = (float*)d_out;

    const bool use_labs = ws_size >= NEED_LABS;
    unsigned* labs = use_labs ? (unsigned*)(ws + LABS_OFF_F) : nullptr;

    // zero AWS bins via memset node (DMA); out is zeroed inside pass1
    hipMemsetAsync((void*)(ws + AWS_OFF), 0, BATCH * 208 * sizeof(float), stream);

    dim3 grid(GXB, BATCH);
    pass1<<<grid, 256, 0, stream>>>(emb, inst, kern, tmask, ws, labs, out);
    if (use_labs) pass2<true ><<<grid, 256, 0, stream>>>(emb, inst, tmask, ws, labs, out);
    else          pass2<false><<<grid, 256, 0, stream>>>(emb, inst, tmask, ws, nullptr, out);
}